// Round 6
// baseline (173.695 us; speedup 1.0000x reference)
//
#include <hip/hip_runtime.h>
#include <math.h>

#define NPTS 8192
#define GD 8
#define NCELL (GD*GD*GD)           // 512
#define CELL_H (0.3f/(float)GD)    // 0.0375 > 0.02 alignment radius
#define INV_H ((float)GD/0.3f)
#define ALIGN_T 4.0e-4f            // 0.02^2
#define K5 5

#define QBLOCK 128
#define NPAIRS (NPTS/2)            // 4096 waves, one row-pair each
#define QGRID (NPAIRS/(QBLOCK/64)) // 2048 blocks

// ws layout (bytes)
#define WS_POS    0                // float4[NPTS] sorted (x,y,z,|p|^2)
#define WS_ROT    131072           // float4[NPTS] sorted rotations
#define WS_CSTART 262144           // int[NCELL+1]
#define WS_IDX    266240           // int[NPTS] sorted -> original
#define WS_CNTR   299008           // unsigned int wave-completion counter
#define WS_PART   299024           // float4[NPAIRS] partials (64 KB)
#define WS_GCNT   364576           // int[NCELL]
#define WS_AUX    366624           // int[NPTS] packed (cell | slot<<9)

// ---------------- build stage 1: count ----------------
__global__ __launch_bounds__(256) void gsr_count(
    const float* __restrict__ pos, unsigned char* __restrict__ ws)
{
    int* gcnt = (int*)(ws + WS_GCNT);
    int* aux  = (int*)(ws + WS_AUX);
    int p = blockIdx.x*256 + threadIdx.x;
    float x = pos[3*p], y = pos[3*p+1], z = pos[3*p+2];
    int ix = min((int)(x*INV_H), GD-1);
    int iy = min((int)(y*INV_H), GD-1);
    int iz = min((int)(z*INV_H), GD-1);
    int c = (ix*GD+iy)*GD+iz;
    int slot = atomicAdd(&gcnt[c], 1);
    aux[p] = c | (slot << 9);
}

// ---------------- build stage 2: scan ----------------
__global__ __launch_bounds__(NCELL) void gsr_scan(unsigned char* __restrict__ ws)
{
    const int* gcnt = (const int*)(ws + WS_GCNT);
    int* cellStart  = (int*)(ws + WS_CSTART);
    unsigned int* counter = (unsigned int*)(ws + WS_CNTR);
    __shared__ int sb[NCELL];
    int t = threadIdx.x;
    sb[t] = gcnt[t];
    __syncthreads();
    for (int off = 1; off < NCELL; off <<= 1) {
        int v = (t >= off) ? sb[t-off] : 0;
        __syncthreads();
        sb[t] += v;
        __syncthreads();
    }
    cellStart[t+1] = sb[t];
    if (t == 0) { cellStart[0] = 0; *counter = 0u; }
}

// ---------------- build stage 3: scatter ----------------
__global__ __launch_bounds__(256) void gsr_scatter(
    const float* __restrict__ pos, const float* __restrict__ rot,
    unsigned char* __restrict__ ws)
{
    float4* sPos = (float4*)(ws + WS_POS);
    float4* sRot = (float4*)(ws + WS_ROT);
    const int* cellStart = (const int*)(ws + WS_CSTART);
    int* sIdx = (int*)(ws + WS_IDX);
    const int* aux = (const int*)(ws + WS_AUX);
    int p = blockIdx.x*256 + threadIdx.x;
    int a = aux[p];
    int c = a & (NCELL-1);
    int dst = cellStart[c] + (a >> 9);
    float x = pos[3*p], y = pos[3*p+1], z = pos[3*p+2];
    // identical fmaf shape as query dot product -> self d2 == 0 exactly
    float w = fmaf(x, x, fmaf(y, y, z*z));
    sPos[dst] = make_float4(x, y, z, w);
    sRot[dst] = *(const float4*)(rot + 4*p);
    sIdx[dst] = p;
}

__device__ __forceinline__ int rfl_i(int v) { return __builtin_amdgcn_readfirstlane(v); }
__device__ __forceinline__ float rfl_f(float v) {
    return __int_as_float(__builtin_amdgcn_readfirstlane(__float_as_int(v)));
}

__device__ __forceinline__ void insert5(float (&d)[K5], float v) {
#pragma unroll
    for (int k = 0; k < K5; k++) { float lo = fminf(d[k], v); v = fmaxf(d[k], v); d[k] = lo; }
}

// wave-wide: s8 = sum sqrt of global ranks 1..8, d9 = 9th smallest
__device__ __forceinline__ void wave_merge5(const float (&d)[K5], float& s8, float& d9) {
    float t0=d[0], t1=d[1], t2=d[2], t3=d[3], t4=d[4];
    float ssum = 0.f, m = 0.f;
#pragma unroll
    for (int k = 0; k < 9; k++) {
        m = t0;
#pragma unroll
        for (int o = 32; o > 0; o >>= 1) m = fminf(m, __shfl_xor(m, o, 64));
        bool take = (t0 == m);          // exact ties ~impossible with random floats
        t0 = take ? t1 : t0;
        t1 = take ? t2 : t1;
        t2 = take ? t3 : t2;
        t3 = take ? t4 : t3;
        t4 = take ? 1e30f : t4;
        if (k >= 1) ssum += sqrtf(fmaxf(m, 0.f) + 1e-12f);
    }
    s8 = ssum; d9 = m;
}

__device__ __forceinline__ float ring1_cov(float Px, float Py, float Pz,
                                           int cx, int cy, int cz) {
    float cov = 1e30f;
    if (cx-1 > 0)    cov = fminf(cov, Px - (float)(cx-1)*CELL_H);
    if (cx+1 < GD-1) cov = fminf(cov, (float)(cx+2)*CELL_H - Px);
    if (cy-1 > 0)    cov = fminf(cov, Py - (float)(cy-1)*CELL_H);
    if (cy+1 < GD-1) cov = fminf(cov, (float)(cy+2)*CELL_H - Py);
    if (cz-1 > 0)    cov = fminf(cov, Pz - (float)(cz-1)*CELL_H);
    if (cz+1 < GD-1) cov = fminf(cov, (float)(cz+2)*CELL_H - Pz);
    return cov;
}

// cold exact fallback: expanding Chebyshev shells r>=2 (never overlaps ring-1)
__device__ void knn_fallback(float Px, float Py, float Pz, float Pw,
                             int cx, int cy, int cz, int lane,
                             const int* __restrict__ cellStart,
                             const float4* __restrict__ sPos,
                             float (&d)[K5], float& s8, float& d9)
{
    for (int r = 2; r <= GD; r++) {
        int xlo = max(cx-r,0), xhi = min(cx+r,GD-1);
        int ylo = max(cy-r,0), yhi = min(cy+r,GD-1);
        for (int jx = xlo; jx <= xhi; jx++) {
            int adx = (jx>cx)?(jx-cx):(cx-jx);
            for (int jy = ylo; jy <= yhi; jy++) {
                int ady = (jy>cy)?(jy-cy):(cy-jy);
                int b = (jx*GD+jy)*GD;
                int rs0=0,re0=0, rs1=0,re1=0;
                if (adx==r || ady==r) {
                    rs0 = cellStart[b+max(cz-r,0)];
                    re0 = cellStart[b+min(cz+r,GD-1)+1];
                } else {
                    if (cz-r >= 0)    { rs0=cellStart[b+cz-r]; re0=cellStart[b+cz-r+1]; }
                    if (cz+r <= GD-1) { rs1=cellStart[b+cz+r]; re1=cellStart[b+cz+r+1]; }
                }
#pragma unroll
                for (int pass = 0; pass < 2; pass++) {
                    int rs = pass? rs1: rs0, re = pass? re1: re0;
                    for (int o = rs + lane; o < re; o += 64) {
                        float4 p = sPos[o];
                        float dt = fmaf(Px, p.x, fmaf(Py, p.y, Pz*p.z));
                        float c = fmaf(-2.f, dt, Pw + p.w);
                        insert5(d, c);
                    }
                }
            }
        }
        wave_merge5(d, s8, d9);
        float cv = 1e30f;
        if (cx-r > 0)    cv = fminf(cv, Px - (float)(cx-r)*CELL_H);
        if (cx+r < GD-1) cv = fminf(cv, (float)(cx+r+1)*CELL_H - Px);
        if (cy-r > 0)    cv = fminf(cv, Py - (float)(cy-r)*CELL_H);
        if (cy+r < GD-1) cv = fminf(cv, (float)(cy+r+1)*CELL_H - Py);
        if (cz-r > 0)    cv = fminf(cv, Pz - (float)(cz-r)*CELL_H);
        if (cz+r < GD-1) cv = fminf(cv, (float)(cz+r+1)*CELL_H - Pz);
        if (d9 <= cv*cv) break;
    }
}

// single-row ring-1 scan with alignment (used for mixed-cell pairs, ~1/16)
__device__ void scan_ring1_single(float Px, float Py, float Pz, float Pw,
                                  float4 Q, int sSelf,
                                  int cx, int cy, int cz, int lane,
                                  const int* __restrict__ cellStart,
                                  const float4* __restrict__ sPos,
                                  const float4* __restrict__ sRot,
                                  float (&d)[K5], float& asum, float& acnt)
{
    int zlo = max(cz-1,0), zhi = min(cz+1,GD-1);
#pragma unroll
    for (int dx = -1; dx <= 1; dx++) {
        int jx = cx + dx; if (jx < 0 || jx > GD-1) continue;
#pragma unroll
        for (int dy = -1; dy <= 1; dy++) {
            int jy = cy + dy; if (jy < 0 || jy > GD-1) continue;
            int b = (jx*GD+jy)*GD;
            int rs = cellStart[b+zlo], re = cellStart[b+zhi+1];
            for (int o = rs + lane; o < re; o += 64) {
                float4 p = sPos[o];
                float dt = fmaf(Px, p.x, fmaf(Py, p.y, Pz*p.z));
                float c = fmaf(-2.f, dt, Pw + p.w);
                insert5(d, c);
                bool a = (c < ALIGN_T) & (o != sSelf);
                float4 rt = sRot[o];
                float dq = fmaf(Q.x, rt.x, fmaf(Q.y, rt.y, fmaf(Q.z, rt.z, Q.w*rt.w)));
                asum += a ? (1.f - fabsf(dq)) : 0.f;
                acnt += a ? 1.f : 0.f;
            }
        }
    }
}

// ---------------- query: one wave per adjacent sorted row-pair ----------------
__global__ __launch_bounds__(QBLOCK) void gsr_query(
    const float* __restrict__ scl,
    const float* __restrict__ opa,
    unsigned char* __restrict__ ws,
    float* __restrict__ out)
{
    const float4* sPos = (const float4*)(ws + WS_POS);
    const float4* sRot = (const float4*)(ws + WS_ROT);
    const int* cellStart = (const int*)(ws + WS_CSTART);
    const int* sIdx = (const int*)(ws + WS_IDX);
    unsigned int* counter = (unsigned int*)(ws + WS_CNTR);
    float* partials = (float*)(ws + WS_PART);

    const int lane = threadIdx.x & 63;
    const int wid  = blockIdx.x*(QBLOCK/64) + (threadIdx.x >> 6);  // 0..NPAIRS-1
    const int sA = 2*wid, sB = sA + 1;

    float4 PvA = sPos[sA], PvB = sPos[sB];
    const float PxA = rfl_f(PvA.x), PyA = rfl_f(PvA.y), PzA = rfl_f(PvA.z), PwA = rfl_f(PvA.w);
    const float PxB = rfl_f(PvB.x), PyB = rfl_f(PvB.y), PzB = rfl_f(PvB.z), PwB = rfl_f(PvB.w);
    const float4 QA = sRot[sA], QB = sRot[sB];
    const int cxA = rfl_i(min((int)(PxA*INV_H), GD-1));
    const int cyA = rfl_i(min((int)(PyA*INV_H), GD-1));
    const int czA = rfl_i(min((int)(PzA*INV_H), GD-1));
    const int cxB = rfl_i(min((int)(PxB*INV_H), GD-1));
    const int cyB = rfl_i(min((int)(PyB*INV_H), GD-1));
    const int czB = rfl_i(min((int)(PzB*INV_H), GD-1));

    float dA[K5], dB[K5];
#pragma unroll
    for (int k = 0; k < K5; k++) { dA[k] = 1e30f; dB[k] = 1e30f; }
    float asum = 0.f, acnt = 0.f;

    if (cxA==cxB && cyA==cyB && czA==czB) {
        // shared-neighborhood fast path (~15/16 of pairs)
        int zlo = max(czA-1,0), zhi = min(czA+1,GD-1);
#pragma unroll
        for (int dx = -1; dx <= 1; dx++) {
            int jx = cxA + dx; if (jx < 0 || jx > GD-1) continue;
#pragma unroll
            for (int dy = -1; dy <= 1; dy++) {
                int jy = cyA + dy; if (jy < 0 || jy > GD-1) continue;
                int b = (jx*GD+jy)*GD;
                int rs = cellStart[b+zlo], re = cellStart[b+zhi+1];
                for (int o = rs + lane; o < re; o += 64) {
                    float4 p = sPos[o];
                    float dtA = fmaf(PxA, p.x, fmaf(PyA, p.y, PzA*p.z));
                    float cA = fmaf(-2.f, dtA, PwA + p.w);
                    float dtB = fmaf(PxB, p.x, fmaf(PyB, p.y, PzB*p.z));
                    float cB = fmaf(-2.f, dtB, PwB + p.w);
                    insert5(dA, cA);
                    insert5(dB, cB);
                    bool aA = (cA < ALIGN_T) & (o != sA);
                    bool aB = (cB < ALIGN_T) & (o != sB);
                    float4 rt = sRot[o];
                    float dqA = fmaf(QA.x, rt.x, fmaf(QA.y, rt.y, fmaf(QA.z, rt.z, QA.w*rt.w)));
                    float dqB = fmaf(QB.x, rt.x, fmaf(QB.y, rt.y, fmaf(QB.z, rt.z, QB.w*rt.w)));
                    asum += aA ? (1.f - fabsf(dqA)) : 0.f;
                    acnt += aA ? 1.f : 0.f;
                    asum += aB ? (1.f - fabsf(dqB)) : 0.f;
                    acnt += aB ? 1.f : 0.f;
                }
            }
        }
    } else {
        scan_ring1_single(PxA,PyA,PzA,PwA, QA, sA, cxA,cyA,czA, lane,
                          cellStart, sPos, sRot, dA, asum, acnt);
        scan_ring1_single(PxB,PyB,PzB,PwB, QB, sB, cxB,cyB,czB, lane,
                          cellStart, sPos, sRot, dB, asum, acnt);
    }

    float s8A, d9A, s8B, d9B;
    wave_merge5(dA, s8A, d9A);
    {
        float cov = ring1_cov(PxA,PyA,PzA, cxA,cyA,czA);
        if (!(d9A <= cov*cov))
            knn_fallback(PxA,PyA,PzA,PwA, cxA,cyA,czA, lane, cellStart, sPos, dA, s8A, d9A);
    }
    wave_merge5(dB, s8B, d9B);
    {
        float cov = ring1_cov(PxB,PyB,PzB, cxB,cyB,czB);
        if (!(d9B <= cov*cov))
            knn_fallback(PxB,PyB,PzB,PwB, cxB,cyB,czB, lane, cellStart, sPos, dB, s8B, d9B);
    }

    float flat = 0.f, dens = 0.f;
    if (lane < 2) {
        int srow = lane ? sB : sA;
        float s8 = lane ? s8B : s8A;
        int i = sIdx[srow];
        dens = fabsf(s8*0.125f - 0.01f) * opa[i];
        float ea = expf(scl[3*i]), eb = expf(scl[3*i+1]), ec = expf(scl[3*i+2]);
        float mn = fminf(ea, fminf(eb, ec));
        float mx = fmaxf(ea, fmaxf(eb, ec));
        float md = fminf(fmaxf(ea, eb), fmaxf(fminf(ea, eb), ec));
        flat = logf(mx/(mn+1e-8f)+1e-8f) + 0.1f/(fabsf(mx-md)+0.001f);
    }

    float vals[4] = {asum, acnt, flat, dens};
#pragma unroll
    for (int qi = 0; qi < 4; qi++) {
        float v = vals[qi];
        for (int o = 32; o > 0; o >>= 1) v += __shfl_down(v, o, 64);
        vals[qi] = v;              // lane 0 holds the wave total
    }
    unsigned int old = 0;
    if (lane == 0) {
        *(float4*)(partials + wid*4) = make_float4(vals[0], vals[1], vals[2], vals[3]);
        __threadfence();
        old = atomicAdd(counter, 1u);
    }
    old = __shfl(old, 0, 64);
    if (old == NPAIRS - 1) {       // last-finishing wave does the final reduction
        __threadfence();
        float t0=0.f, t1=0.f, t2=0.f, t3=0.f;
        for (int b = lane; b < NPAIRS; b += 64) {
            float4 pv = *(const float4*)(partials + b*4);
            t0 += pv.x; t1 += pv.y; t2 += pv.z; t3 += pv.w;
        }
#pragma unroll
        for (int o = 32; o > 0; o >>= 1) {
            t0 += __shfl_down(t0, o, 64); t1 += __shfl_down(t1, o, 64);
            t2 += __shfl_down(t2, o, 64); t3 += __shfl_down(t3, o, 64);
        }
        if (lane == 0) {
            float flat_loss = -t2 / (float)NPTS;
            float align_loss = (t1 > 0.f) ? (t0/t1) : 0.f;
            float dens_loss = t3 / (float)NPTS;
            out[0] = 1.0f*flat_loss + 0.5f*align_loss + 0.2f*dens_loss;
        }
    }
}

extern "C" void kernel_launch(void* const* d_in, const int* in_sizes, int n_in,
                              void* d_out, int out_size, void* d_ws, size_t ws_size,
                              hipStream_t stream) {
    const float* pos = (const float*)d_in[0];
    const float* rot = (const float*)d_in[1];
    const float* scl = (const float*)d_in[2];
    const float* opa = (const float*)d_in[3];
    unsigned char* ws = (unsigned char*)d_ws;

    hipMemsetAsync(ws + WS_GCNT, 0, NCELL*sizeof(int), stream);
    gsr_count  <<<NPTS/256, 256, 0, stream>>>(pos, ws);
    gsr_scan   <<<1, NCELL, 0, stream>>>(ws);
    gsr_scatter<<<NPTS/256, 256, 0, stream>>>(pos, rot, ws);
    gsr_query  <<<QGRID, QBLOCK, 0, stream>>>(scl, opa, ws, (float*)d_out);
}

// Round 7
// 108.362 us; speedup vs baseline: 1.6029x; 1.6029x over previous
//
#include <hip/hip_runtime.h>
#include <math.h>

#define NPTS 8192
#define GD 12
#define NCELL (GD*GD*GD)           // 1728
#define NCPAD 2048                 // padded cell count (pow2 for packing/scan)
#define CELL_H (0.3f/(float)GD)    // 0.025 > 0.02 alignment radius
#define INV_H ((float)GD/0.3f)     // 40.0
#define ALIGN_T 4.0e-4f            // 0.02^2
#define K5 5

#define QBLOCK 512
#define QWAVES (QBLOCK/64)         // 8 rows per block
#define QGRID (NPTS/QWAVES)        // 1024 blocks

// ws layout (bytes)
#define WS_POS    0                // float4[NPTS] sorted (x,y,z,|p|^2)
#define WS_ROT    131072           // float4[NPTS] sorted rotations
#define WS_CSTART 262144           // int[NCPAD+4]
#define WS_IDX    270352           // int[NPTS] sorted -> original
#define WS_CNTR   303120           // unsigned int block-completion counter
#define WS_PART   303152           // float4[QGRID] partials (16 KB)
#define WS_GCNT   319536           // int[NCPAD] cell counts
#define WS_AUX    327728           // int[NPTS] packed (cell | slot<<11)

// ---------------- build stage 1: count ----------------
__global__ __launch_bounds__(256) void gsr_count(
    const float* __restrict__ pos, unsigned char* __restrict__ ws)
{
    int* gcnt = (int*)(ws + WS_GCNT);
    int* aux  = (int*)(ws + WS_AUX);
    int p = blockIdx.x*256 + threadIdx.x;
    float x = pos[3*p], y = pos[3*p+1], z = pos[3*p+2];
    int ix = min((int)(x*INV_H), GD-1);
    int iy = min((int)(y*INV_H), GD-1);
    int iz = min((int)(z*INV_H), GD-1);
    int c = (ix*GD+iy)*GD+iz;
    int slot = atomicAdd(&gcnt[c], 1);
    aux[p] = c | (slot << 11);
}

// ---------------- build stage 2: scan (1 block, 2 cells/thread) ----------------
__global__ __launch_bounds__(1024) void gsr_scan(unsigned char* __restrict__ ws)
{
    const int* gcnt = (const int*)(ws + WS_GCNT);
    int* cellStart  = (int*)(ws + WS_CSTART);
    unsigned int* counter = (unsigned int*)(ws + WS_CNTR);
    __shared__ int sb[1024];
    int t = threadIdx.x;
    int c0 = gcnt[2*t], c1 = gcnt[2*t+1];
    sb[t] = c0 + c1;
    __syncthreads();
    for (int off = 1; off < 1024; off <<= 1) {
        int v = (t >= off) ? sb[t-off] : 0;
        __syncthreads();
        sb[t] += v;
        __syncthreads();
    }
    int incl = sb[t];
    int excl = incl - c0 - c1;
    cellStart[2*t]   = excl;
    cellStart[2*t+1] = excl + c0;
    if (t == 1023) cellStart[2048] = incl;
    if (t == 0) *counter = 0u;
}

// ---------------- build stage 3: scatter ----------------
__global__ __launch_bounds__(256) void gsr_scatter(
    const float* __restrict__ pos, const float* __restrict__ rot,
    unsigned char* __restrict__ ws)
{
    float4* sPos = (float4*)(ws + WS_POS);
    float4* sRot = (float4*)(ws + WS_ROT);
    const int* cellStart = (const int*)(ws + WS_CSTART);
    int* sIdx = (int*)(ws + WS_IDX);
    const int* aux = (const int*)(ws + WS_AUX);
    int p = blockIdx.x*256 + threadIdx.x;
    int a = aux[p];
    int c = a & (NCPAD-1);
    int dst = cellStart[c] + (a >> 11);
    float x = pos[3*p], y = pos[3*p+1], z = pos[3*p+2];
    // identical fmaf shape as query dot product -> self d2 == 0 exactly
    float w = fmaf(x, x, fmaf(y, y, z*z));
    sPos[dst] = make_float4(x, y, z, w);
    sRot[dst] = *(const float4*)(rot + 4*p);
    sIdx[dst] = p;
}

__device__ __forceinline__ int rfl_i(int v) { return __builtin_amdgcn_readfirstlane(v); }
__device__ __forceinline__ float rfl_f(float v) {
    return __int_as_float(__builtin_amdgcn_readfirstlane(__float_as_int(v)));
}

__device__ __forceinline__ void insert5(float (&d)[K5], float v) {
#pragma unroll
    for (int k = 0; k < K5; k++) { float lo = fminf(d[k], v); v = fmaxf(d[k], v); d[k] = lo; }
}

// wave-wide: s8 = sum sqrt of global ranks 1..8, d9 = 9th smallest (R6-proven exact)
__device__ __forceinline__ void wave_merge5(const float (&d)[K5], float& s8, float& d9) {
    float t0=d[0], t1=d[1], t2=d[2], t3=d[3], t4=d[4];
    float ssum = 0.f, m = 0.f;
#pragma unroll
    for (int k = 0; k < 9; k++) {
        m = t0;
#pragma unroll
        for (int o = 32; o > 0; o >>= 1) m = fminf(m, __shfl_xor(m, o, 64));
        bool take = (t0 == m);
        t0 = take ? t1 : t0;
        t1 = take ? t2 : t1;
        t2 = take ? t3 : t2;
        t3 = take ? t4 : t3;
        t4 = take ? 1e30f : t4;
        if (k >= 1) ssum += sqrtf(fmaxf(m, 0.f) + 1e-12f);
    }
    s8 = ssum; d9 = m;
}

// ---------------- query: one wave per sorted row ----------------
__global__ __launch_bounds__(QBLOCK) void gsr_query(
    const float* __restrict__ scl,
    const float* __restrict__ opa,
    unsigned char* __restrict__ ws,
    float* __restrict__ out)
{
    const float4* sPos = (const float4*)(ws + WS_POS);
    const float4* sRot = (const float4*)(ws + WS_ROT);
    const int* cellStart = (const int*)(ws + WS_CSTART);
    const int* sIdx = (const int*)(ws + WS_IDX);
    unsigned int* counter = (unsigned int*)(ws + WS_CNTR);
    float* partials = (float*)(ws + WS_PART);

    __shared__ float red[QWAVES][4];
    __shared__ int lastflag;

    const int tid = threadIdx.x;
    const int lane = tid & 63;
    const int wv = tid >> 6;
    const int s = blockIdx.x*QWAVES + wv;       // sorted slot = row (uniform)

    const float4 Pv = sPos[s];
    const float Px = rfl_f(Pv.x), Py = rfl_f(Pv.y), Pz = rfl_f(Pv.z), Pw = rfl_f(Pv.w);
    const float4 Q = sRot[s];
    const int cx = rfl_i(min((int)(Px*INV_H), GD-1));
    const int cy = rfl_i(min((int)(Py*INV_H), GD-1));
    const int cz = rfl_i(min((int)(Pz*INV_H), GD-1));
    const int zlo = max(cz-1, 0), zhi = min(cz+1, GD-1);

    // ---- scalar prefix of the 9 column ranges (all SGPR work) ----
    int rsv[9], O[10];
    O[0] = 0;
    {
        int idx = 0;
#pragma unroll
        for (int dx = -1; dx <= 1; dx++) {
            int jx = cx + dx;
            bool vx = (jx >= 0) && (jx <= GD-1);
#pragma unroll
            for (int dy = -1; dy <= 1; dy++) {
                int jy = cy + dy;
                bool v = vx && (jy >= 0) && (jy <= GD-1);
                int b = v ? ((jx*GD + jy)*GD) : 0;
                int lo = cellStart[b + zlo];
                int hi = cellStart[b + zhi + 1];
                int len = v ? (hi - lo) : 0;
                rsv[idx] = lo;
                O[idx+1] = O[idx] + len;
                idx++;
            }
        }
    }
    const int T = O[9];

    float d[K5];
#pragma unroll
    for (int k = 0; k < K5; k++) d[k] = 1e30f;
    float asum = 0.f, acnt = 0.f;

    // ---- flattened ring-1 scan: full-utilization candidate loop ----
    for (int g = lane; g < T; g += 64) {
        int o = 0;
#pragma unroll
        for (int i = 0; i < 9; i++) {
            bool in = (g >= O[i]) && (g < O[i+1]);
            o = in ? (rsv[i] + (g - O[i])) : o;
        }
        float4 p = sPos[o];
        float4 rt = sRot[o];
        float dt = fmaf(Px, p.x, fmaf(Py, p.y, Pz*p.z));
        float c = fmaf(-2.f, dt, Pw + p.w);     // d^2, self == 0 exact
        insert5(d, c);
        bool a = (c < ALIGN_T) & (o != s);
        float dq = fmaf(Q.x, rt.x, fmaf(Q.y, rt.y, fmaf(Q.z, rt.z, Q.w*rt.w)));
        asum += a ? (1.f - fabsf(dq)) : 0.f;
        acnt += a ? 1.f : 0.f;
    }

    float s8, d9;
    wave_merge5(d, s8, d9);

    // coverage radius of ring-1 box (interior faces only)
    float cov = 1e30f;
    if (cx-1 > 0)    cov = fminf(cov, Px - (float)(cx-1)*CELL_H);
    if (cx+1 < GD-1) cov = fminf(cov, (float)(cx+2)*CELL_H - Px);
    if (cy-1 > 0)    cov = fminf(cov, Py - (float)(cy-1)*CELL_H);
    if (cy+1 < GD-1) cov = fminf(cov, (float)(cy+2)*CELL_H - Py);
    if (cz-1 > 0)    cov = fminf(cov, Pz - (float)(cz-1)*CELL_H);
    if (cz+1 < GD-1) cov = fminf(cov, (float)(cz+2)*CELL_H - Pz);

    if (!(d9 <= cov*cov)) {
        // ---- cold exact fallback: expanding Chebyshev shells r>=2 ----
        for (int r = 2; r <= GD; r++) {
            int xlo2 = max(cx-r,0), xhi2 = min(cx+r,GD-1);
            int ylo2 = max(cy-r,0), yhi2 = min(cy+r,GD-1);
            for (int jx = xlo2; jx <= xhi2; jx++) {
                int adx = (jx>cx)?(jx-cx):(cx-jx);
                for (int jy = ylo2; jy <= yhi2; jy++) {
                    int ady = (jy>cy)?(jy-cy):(cy-jy);
                    int b = (jx*GD+jy)*GD;
                    int rs0=0,re0=0, rs1=0,re1=0;
                    if (adx==r || ady==r) {
                        rs0 = cellStart[b+max(cz-r,0)];
                        re0 = cellStart[b+min(cz+r,GD-1)+1];
                    } else {
                        if (cz-r >= 0)    { rs0=cellStart[b+cz-r]; re0=cellStart[b+cz-r+1]; }
                        if (cz+r <= GD-1) { rs1=cellStart[b+cz+r]; re1=cellStart[b+cz+r+1]; }
                    }
#pragma unroll
                    for (int pass = 0; pass < 2; pass++) {
                        int rs = pass? rs1: rs0, re = pass? re1: re0;
                        for (int o = rs + lane; o < re; o += 64) {
                            float4 p = sPos[o];
                            float dt = fmaf(Px, p.x, fmaf(Py, p.y, Pz*p.z));
                            float c = fmaf(-2.f, dt, Pw + p.w);
                            insert5(d, c);
                        }
                    }
                }
            }
            wave_merge5(d, s8, d9);
            float cv = 1e30f;
            if (cx-r > 0)    cv = fminf(cv, Px - (float)(cx-r)*CELL_H);
            if (cx+r < GD-1) cv = fminf(cv, (float)(cx+r+1)*CELL_H - Px);
            if (cy-r > 0)    cv = fminf(cv, Py - (float)(cy-r)*CELL_H);
            if (cy+r < GD-1) cv = fminf(cv, (float)(cy+r+1)*CELL_H - Py);
            if (cz-r > 0)    cv = fminf(cv, Pz - (float)(cz-r)*CELL_H);
            if (cz+r < GD-1) cv = fminf(cv, (float)(cz+r+1)*CELL_H - Pz);
            if (d9 <= cv*cv) break;
        }
    }

    float flat = 0.f, dens = 0.f;
    if (lane == 0) {
        int i = sIdx[s];
        dens = fabsf(s8*0.125f - 0.01f) * opa[i];
        float ea = expf(scl[3*i]), eb = expf(scl[3*i+1]), ec = expf(scl[3*i+2]);
        float mn = fminf(ea, fminf(eb, ec));
        float mx = fmaxf(ea, fmaxf(eb, ec));
        float md = fminf(fmaxf(ea, eb), fmaxf(fminf(ea, eb), ec));
        flat = logf(mx/(mn+1e-8f)+1e-8f) + 0.1f/(fabsf(mx-md)+0.001f);
    }

    float vals[4] = {asum, acnt, flat, dens};
#pragma unroll
    for (int qi = 0; qi < 4; qi++) {
        float v = vals[qi];
        for (int o = 32; o > 0; o >>= 1) v += __shfl_down(v, o, 64);
        if (lane == 0) red[wv][qi] = v;
    }
    __syncthreads();
    if (tid == 0) {
        float t0=0,t1=0,t2=0,t3=0;
        for (int w = 0; w < QWAVES; w++) { t0+=red[w][0]; t1+=red[w][1]; t2+=red[w][2]; t3+=red[w][3]; }
        *(float4*)(partials + blockIdx.x*4) = make_float4(t0,t1,t2,t3);
        __threadfence();
        unsigned int old = atomicAdd(counter, 1u);
        lastflag = (old == QGRID-1) ? 1 : 0;
    }
    __syncthreads();
    if (lastflag && wv == 0) {
        __threadfence();
        float t0=0,t1=0,t2=0,t3=0;
        for (int b = lane; b < QGRID; b += 64) {
            float4 pv = *(const float4*)(partials + b*4);
            t0+=pv.x; t1+=pv.y; t2+=pv.z; t3+=pv.w;
        }
#pragma unroll
        for (int o = 32; o > 0; o >>= 1) {
            t0+=__shfl_down(t0,o,64); t1+=__shfl_down(t1,o,64);
            t2+=__shfl_down(t2,o,64); t3+=__shfl_down(t3,o,64);
        }
        if (lane == 0) {
            float flat_loss = -t2 / (float)NPTS;
            float align_loss = (t1 > 0.f) ? (t0/t1) : 0.f;
            float dens_loss = t3 / (float)NPTS;
            out[0] = 1.0f*flat_loss + 0.5f*align_loss + 0.2f*dens_loss;
        }
    }
}

extern "C" void kernel_launch(void* const* d_in, const int* in_sizes, int n_in,
                              void* d_out, int out_size, void* d_ws, size_t ws_size,
                              hipStream_t stream) {
    const float* pos = (const float*)d_in[0];
    const float* rot = (const float*)d_in[1];
    const float* scl = (const float*)d_in[2];
    const float* opa = (const float*)d_in[3];
    unsigned char* ws = (unsigned char*)d_ws;

    hipMemsetAsync(ws + WS_GCNT, 0, NCPAD*sizeof(int), stream);
    gsr_count  <<<NPTS/256, 256, 0, stream>>>(pos, ws);
    gsr_scan   <<<1, 1024, 0, stream>>>(ws);
    gsr_scatter<<<NPTS/256, 256, 0, stream>>>(pos, rot, ws);
    gsr_query  <<<QGRID, QBLOCK, 0, stream>>>(scl, opa, ws, (float*)d_out);
}

// Round 8
// 106.072 us; speedup vs baseline: 1.6375x; 1.0216x over previous
//
#include <hip/hip_runtime.h>
#include <math.h>

#define NPTS 8192
#define GD 12
#define NCPAD 2048                 // padded cell count
#define CELL_H (0.3f/(float)GD)    // 0.025 > 0.02 alignment radius
#define INV_H ((float)GD/0.3f)     // 40.0
#define ALIGN_T 4.0e-4f            // 0.02^2
#define K9 9

#define MBLOCKS 512                // main query: 16 rows/block, 1 wave
#define FBLOCKS 256                // fallback: 4 waves/block
#define TOTBLK (MBLOCKS+FBLOCKS)   // 768 completion slots

// ws layout (bytes)
#define WS_POS    0                // float4[NPTS] sorted (x,y,z,|p|^2)
#define WS_ROT    131072           // float4[NPTS] sorted rotations
#define WS_CSTART 262144           // int[NCPAD+1]
#define WS_IDX    270352           // int[NPTS] sorted -> original
#define WS_CNTR   303120           // uint completion counter
#define WS_WCNT   303124           // uint worklist count
#define WS_PART   303152           // float4[TOTBLK]
#define WS_GCNT   319536           // int[NCPAD]
#define WS_AUX    327728           // int[NPTS] packed (cell | slot<<11)
#define WS_WL     360496           // int[NPTS] worklist

// ---------------- build stage 1: count ----------------
__global__ __launch_bounds__(256) void gsr_count(
    const float* __restrict__ pos, unsigned char* __restrict__ ws)
{
    int* gcnt = (int*)(ws + WS_GCNT);
    int* aux  = (int*)(ws + WS_AUX);
    int p = blockIdx.x*256 + threadIdx.x;
    float x = pos[3*p], y = pos[3*p+1], z = pos[3*p+2];
    int ix = min((int)(x*INV_H), GD-1);
    int iy = min((int)(y*INV_H), GD-1);
    int iz = min((int)(z*INV_H), GD-1);
    int c = (ix*GD+iy)*GD+iz;
    int slot = atomicAdd(&gcnt[c], 1);
    aux[p] = c | (slot << 11);
}

// ---------------- build stage 2: scan ----------------
__global__ __launch_bounds__(1024) void gsr_scan(unsigned char* __restrict__ ws)
{
    const int* gcnt = (const int*)(ws + WS_GCNT);
    int* cellStart  = (int*)(ws + WS_CSTART);
    unsigned int* counter = (unsigned int*)(ws + WS_CNTR);
    unsigned int* wcnt    = (unsigned int*)(ws + WS_WCNT);
    __shared__ int sb[1024];
    int t = threadIdx.x;
    int c0 = gcnt[2*t], c1 = gcnt[2*t+1];
    sb[t] = c0 + c1;
    __syncthreads();
    for (int off = 1; off < 1024; off <<= 1) {
        int v = (t >= off) ? sb[t-off] : 0;
        __syncthreads();
        sb[t] += v;
        __syncthreads();
    }
    int incl = sb[t];
    int excl = incl - c0 - c1;
    cellStart[2*t]   = excl;
    cellStart[2*t+1] = excl + c0;
    if (t == 1023) cellStart[2048] = incl;
    if (t == 0) { *counter = 0u; *wcnt = 0u; }
}

// ---------------- build stage 3: scatter ----------------
__global__ __launch_bounds__(256) void gsr_scatter(
    const float* __restrict__ pos, const float* __restrict__ rot,
    unsigned char* __restrict__ ws)
{
    float4* sPos = (float4*)(ws + WS_POS);
    float4* sRot = (float4*)(ws + WS_ROT);
    const int* cellStart = (const int*)(ws + WS_CSTART);
    int* sIdx = (int*)(ws + WS_IDX);
    const int* aux = (const int*)(ws + WS_AUX);
    int p = blockIdx.x*256 + threadIdx.x;
    int a = aux[p];
    int c = a & (NCPAD-1);
    int dst = cellStart[c] + (a >> 11);
    float x = pos[3*p], y = pos[3*p+1], z = pos[3*p+2];
    // identical fmaf shape as query dot product -> self d2 == 0 exactly
    float w = fmaf(x, x, fmaf(y, y, z*z));
    sPos[dst] = make_float4(x, y, z, w);
    sRot[dst] = *(const float4*)(rot + 4*p);
    sIdx[dst] = p;
}

__device__ __forceinline__ int rfl_i(int v) { return __builtin_amdgcn_readfirstlane(v); }
__device__ __forceinline__ float rfl_f(float v) {
    return __int_as_float(__builtin_amdgcn_readfirstlane(__float_as_int(v)));
}

__device__ __forceinline__ void insert9(float (&d)[K9], float v) {
#pragma unroll
    for (int k = 0; k < K9; k++) { float lo = fminf(d[k], v); v = fmaxf(d[k], v); d[k] = lo; }
}

// extract-min wave merge over 9-deep lists (used ONLY in the rare fallback kernel)
__device__ __forceinline__ void wave_merge9x(const float (&dd)[K9], float& s8, float& d9) {
    float t0=dd[0],t1=dd[1],t2=dd[2],t3=dd[3],t4=dd[4],t5=dd[5],t6=dd[6],t7=dd[7],t8=dd[8];
    float ssum = 0.f, m = 0.f;
#pragma unroll
    for (int k = 0; k < 9; k++) {
        m = t0;
#pragma unroll
        for (int o = 32; o > 0; o >>= 1) m = fminf(m, __shfl_xor(m, o, 64));
        bool take = (t0 == m);
        t0=take?t1:t0; t1=take?t2:t1; t2=take?t3:t2; t3=take?t4:t3;
        t4=take?t5:t4; t5=take?t6:t5; t6=take?t7:t6; t7=take?t8:t7;
        t8=take?1e30f:t8;
        if (k >= 1) ssum += sqrtf(fmaxf(m, 0.f) + 1e-12f);
    }
    s8 = ssum; d9 = m;
}

// ---------------- main query: 16 rows/wave, 4 lanes/row ----------------
__global__ __launch_bounds__(64) void gsr_qmain(
    const float* __restrict__ scl,
    const float* __restrict__ opa,
    unsigned char* __restrict__ ws)
{
    const float4* sPos = (const float4*)(ws + WS_POS);
    const float4* sRot = (const float4*)(ws + WS_ROT);
    const int* cellStart = (const int*)(ws + WS_CSTART);
    const int* sIdx = (const int*)(ws + WS_IDX);
    unsigned int* counter = (unsigned int*)(ws + WS_CNTR);
    unsigned int* wcnt    = (unsigned int*)(ws + WS_WCNT);
    int* wl = (int*)(ws + WS_WL);
    float* partials = (float*)(ws + WS_PART);

    const int lane = threadIdx.x;          // 0..63, single wave
    const int r16  = lane & 15;            // row within block
    const int sub  = lane >> 4;            // quarter 0..3
    const int s = blockIdx.x*16 + r16;     // sorted row

    const float4 Pv = sPos[s];
    const float4 Q  = sRot[s];
    const float Px = Pv.x, Py = Pv.y, Pz = Pv.z, Pw = Pv.w;
    const int cx = min((int)(Px*INV_H), GD-1);
    const int cy = min((int)(Py*INV_H), GD-1);
    const int cz = min((int)(Pz*INV_H), GD-1);
    const int zlo = max(cz-1, 0), zhi = min(cz+1, GD-1);

    // per-lane 9 column ranges, quartered by sub
    int rsv[9], tq0[9], tq1[9];
    {
        int idx = 0;
#pragma unroll
        for (int dx = -1; dx <= 1; dx++) {
#pragma unroll
            for (int dy = -1; dy <= 1; dy++) {
                int jx = cx + dx, jy = cy + dy;
                bool v = (jx >= 0) & (jx < GD) & (jy >= 0) & (jy < GD);
                int b = v ? ((jx*GD + jy)*GD) : 0;
                int lo = cellStart[b + zlo];
                int hi = cellStart[b + zhi + 1];
                int len = v ? (hi - lo) : 0;
                rsv[idx] = lo;
                tq0[idx] = (len*sub) >> 2;
                tq1[idx] = (len*(sub+1)) >> 2;
                idx++;
            }
        }
    }

    float d[K9];
#pragma unroll
    for (int k = 0; k < K9; k++) d[k] = 1e30f;
    float asum = 0.f, acnt = 0.f;

#pragma unroll
    for (int i = 0; i < 9; i++) {
        for (int t = tq0[i]; t < tq1[i]; t++) {
            int o = rsv[i] + t;
            float4 p = sPos[o];
            float4 rt = sRot[o];
            float dt = fmaf(Px, p.x, fmaf(Py, p.y, Pz*p.z));
            float c = fmaf(-2.f, dt, Pw + p.w);       // d^2, self == 0 exact
            insert9(d, c);
            bool a = (c < ALIGN_T) & (o != s);
            float dq = fmaf(Q.x, rt.x, fmaf(Q.y, rt.y, fmaf(Q.z, rt.z, Q.w*rt.w)));
            asum += a ? (1.f - fabsf(dq)) : 0.f;
            acnt += a ? 1.f : 0.f;
        }
    }

    // 2-stage butterfly merge of the 4 quarter-lists per row (exact: K9 + K9 -> top9)
#pragma unroll
    for (int st = 0; st < 2; st++) {
        const int off = st ? 16 : 32;
        float t[K9];
#pragma unroll
        for (int k = 0; k < K9; k++) t[k] = __shfl_xor(d[k], off, 64);
#pragma unroll
        for (int m = 0; m < K9; m++) insert9(d, t[m]);
    }

    float flat = 0.f, dens = 0.f;
    if (sub == 0) {
        float d9 = d[8];
        float s8 = 0.f;
#pragma unroll
        for (int k = 1; k < K9; k++) s8 += sqrtf(fmaxf(d[k], 0.f) + 1e-12f);
        float cov = 1e30f;
        if (cx-1 > 0)    cov = fminf(cov, Px - (float)(cx-1)*CELL_H);
        if (cx+1 < GD-1) cov = fminf(cov, (float)(cx+2)*CELL_H - Px);
        if (cy-1 > 0)    cov = fminf(cov, Py - (float)(cy-1)*CELL_H);
        if (cy+1 < GD-1) cov = fminf(cov, (float)(cy+2)*CELL_H - Py);
        if (cz-1 > 0)    cov = fminf(cov, Pz - (float)(cz-1)*CELL_H);
        if (cz+1 < GD-1) cov = fminf(cov, (float)(cz+2)*CELL_H - Pz);
        bool fb = !(d9 <= cov*cov);
        int i = sIdx[s];
        float ea = expf(scl[3*i]), eb = expf(scl[3*i+1]), ec = expf(scl[3*i+2]);
        float mn = fminf(ea, fminf(eb, ec));
        float mx = fmaxf(ea, fmaxf(eb, ec));
        float md = fminf(fmaxf(ea, eb), fmaxf(fminf(ea, eb), ec));
        flat = logf(mx/(mn+1e-8f)+1e-8f) + 0.1f/(fabsf(mx-md)+0.001f);
        if (fb) {
            int wi = (int)atomicAdd(wcnt, 1u);     // defer dens to fallback kernel
            wl[wi] = s;
        } else {
            dens = fabsf(s8*0.125f - 0.01f) * opa[i];
        }
    }

    float vals[4] = {asum, acnt, flat, dens};
#pragma unroll
    for (int qi = 0; qi < 4; qi++) {
        float v = vals[qi];
        for (int o = 32; o > 0; o >>= 1) v += __shfl_down(v, o, 64);
        vals[qi] = v;
    }
    if (lane == 0) {
        *(float4*)(partials + blockIdx.x*4) = make_float4(vals[0], vals[1], vals[2], vals[3]);
        __threadfence();
        atomicAdd(counter, 1u);     // main blocks can never be the last finisher (fallback runs after)
    }
}

// ---------------- fallback: dens for coverage-failing rows + final combine ----------------
__global__ __launch_bounds__(256) void gsr_qfb(
    const float* __restrict__ opa,
    unsigned char* __restrict__ ws,
    float* __restrict__ out)
{
    const float4* sPos = (const float4*)(ws + WS_POS);
    const int* cellStart = (const int*)(ws + WS_CSTART);
    const int* sIdx = (const int*)(ws + WS_IDX);
    unsigned int* counter = (unsigned int*)(ws + WS_CNTR);
    const unsigned int* wcnt = (const unsigned int*)(ws + WS_WCNT);
    const int* wl = (const int*)(ws + WS_WL);
    float* partials = (float*)(ws + WS_PART);

    __shared__ float redD[4];
    __shared__ int lastflag;

    const int tid = threadIdx.x;
    const int lane = tid & 63;
    const int wv = tid >> 6;
    const unsigned int wc = *wcnt;

    float densAcc = 0.f;
    for (int j = blockIdx.x*4 + wv; j < (int)wc; j += FBLOCKS*4) {
        const int s = wl[j];
        const float4 Pv = sPos[s];
        const float Px = rfl_f(Pv.x), Py = rfl_f(Pv.y), Pz = rfl_f(Pv.z), Pw = rfl_f(Pv.w);
        const int cx = rfl_i(min((int)(Px*INV_H), GD-1));
        const int cy = rfl_i(min((int)(Py*INV_H), GD-1));
        const int cz = rfl_i(min((int)(Pz*INV_H), GD-1));

        float d[K9];
#pragma unroll
        for (int k = 0; k < K9; k++) d[k] = 1e30f;

        // full 5x5x5 box (r=2), from scratch
        {
            int zl = max(cz-2, 0), zh = min(cz+2, GD-1);
            for (int jx = max(cx-2,0); jx <= min(cx+2,GD-1); jx++) {
                for (int jy = max(cy-2,0); jy <= min(cy+2,GD-1); jy++) {
                    int b = (jx*GD+jy)*GD;
                    int rs = cellStart[b+zl], re = cellStart[b+zh+1];
                    for (int o = rs + lane; o < re; o += 64) {
                        float4 p = sPos[o];
                        float dt = fmaf(Px, p.x, fmaf(Py, p.y, Pz*p.z));
                        float c = fmaf(-2.f, dt, Pw + p.w);
                        insert9(d, c);
                    }
                }
            }
        }
        float s8, d9;
        wave_merge9x(d, s8, d9);
        {
            float cov = 1e30f;
            if (cx-2 > 0)    cov = fminf(cov, Px - (float)(cx-2)*CELL_H);
            if (cx+2 < GD-1) cov = fminf(cov, (float)(cx+3)*CELL_H - Px);
            if (cy-2 > 0)    cov = fminf(cov, Py - (float)(cy-2)*CELL_H);
            if (cy+2 < GD-1) cov = fminf(cov, (float)(cy+3)*CELL_H - Py);
            if (cz-2 > 0)    cov = fminf(cov, Pz - (float)(cz-2)*CELL_H);
            if (cz+2 < GD-1) cov = fminf(cov, (float)(cz+3)*CELL_H - Pz);
            if (!(d9 <= cov*cov)) {
                // expanding Chebyshev shells r>=3 (provably exact, ~never runs)
                for (int r = 3; r <= GD; r++) {
                    int xlo = max(cx-r,0), xhi = min(cx+r,GD-1);
                    int ylo = max(cy-r,0), yhi = min(cy+r,GD-1);
                    for (int jx = xlo; jx <= xhi; jx++) {
                        int adx = (jx>cx)?(jx-cx):(cx-jx);
                        for (int jy = ylo; jy <= yhi; jy++) {
                            int ady = (jy>cy)?(jy-cy):(cy-jy);
                            int b = (jx*GD+jy)*GD;
                            int rs0=0,re0=0, rs1=0,re1=0;
                            if (adx==r || ady==r) {
                                rs0 = cellStart[b+max(cz-r,0)];
                                re0 = cellStart[b+min(cz+r,GD-1)+1];
                            } else {
                                if (cz-r >= 0)    { rs0=cellStart[b+cz-r]; re0=cellStart[b+cz-r+1]; }
                                if (cz+r <= GD-1) { rs1=cellStart[b+cz+r]; re1=cellStart[b+cz+r+1]; }
                            }
#pragma unroll
                            for (int pass = 0; pass < 2; pass++) {
                                int rs = pass? rs1: rs0, re = pass? re1: re0;
                                for (int o = rs + lane; o < re; o += 64) {
                                    float4 p = sPos[o];
                                    float dt = fmaf(Px, p.x, fmaf(Py, p.y, Pz*p.z));
                                    float c = fmaf(-2.f, dt, Pw + p.w);
                                    insert9(d, c);
                                }
                            }
                        }
                    }
                    wave_merge9x(d, s8, d9);
                    float cv = 1e30f;
                    if (cx-r > 0)    cv = fminf(cv, Px - (float)(cx-r)*CELL_H);
                    if (cx+r < GD-1) cv = fminf(cv, (float)(cx+r+1)*CELL_H - Px);
                    if (cy-r > 0)    cv = fminf(cv, Py - (float)(cy-r)*CELL_H);
                    if (cy+r < GD-1) cv = fminf(cv, (float)(cy+r+1)*CELL_H - Py);
                    if (cz-r > 0)    cv = fminf(cv, Pz - (float)(cz-r)*CELL_H);
                    if (cz+r < GD-1) cv = fminf(cv, (float)(cz+r+1)*CELL_H - Pz);
                    if (d9 <= cv*cv) break;
                }
            }
        }
        if (lane == 0) densAcc += fabsf(s8*0.125f - 0.01f) * opa[sIdx[s]];
    }

    if (lane == 0) redD[wv] = densAcc;
    __syncthreads();
    if (tid == 0) {
        float dsum = redD[0] + redD[1] + redD[2] + redD[3];
        *(float4*)(partials + (MBLOCKS + blockIdx.x)*4) = make_float4(0.f, 0.f, 0.f, dsum);
        __threadfence();
        unsigned int old = atomicAdd(counter, 1u);
        lastflag = (old == TOTBLK-1) ? 1 : 0;
    }
    __syncthreads();
    if (lastflag && tid < 64) {
        __threadfence();
        float t0=0.f, t1=0.f, t2=0.f, t3=0.f;
        for (int b = lane; b < TOTBLK; b += 64) {
            float4 pv = *(const float4*)(partials + b*4);
            t0 += pv.x; t1 += pv.y; t2 += pv.z; t3 += pv.w;
        }
#pragma unroll
        for (int o = 32; o > 0; o >>= 1) {
            t0 += __shfl_down(t0, o, 64); t1 += __shfl_down(t1, o, 64);
            t2 += __shfl_down(t2, o, 64); t3 += __shfl_down(t3, o, 64);
        }
        if (lane == 0) {
            float flat_loss = -t2 / (float)NPTS;
            float align_loss = (t1 > 0.f) ? (t0/t1) : 0.f;
            float dens_loss = t3 / (float)NPTS;
            out[0] = 1.0f*flat_loss + 0.5f*align_loss + 0.2f*dens_loss;
        }
    }
}

extern "C" void kernel_launch(void* const* d_in, const int* in_sizes, int n_in,
                              void* d_out, int out_size, void* d_ws, size_t ws_size,
                              hipStream_t stream) {
    const float* pos = (const float*)d_in[0];
    const float* rot = (const float*)d_in[1];
    const float* scl = (const float*)d_in[2];
    const float* opa = (const float*)d_in[3];
    unsigned char* ws = (unsigned char*)d_ws;

    hipMemsetAsync(ws + WS_GCNT, 0, NCPAD*sizeof(int), stream);
    gsr_count  <<<NPTS/256, 256, 0, stream>>>(pos, ws);
    gsr_scan   <<<1, 1024, 0, stream>>>(ws);
    gsr_scatter<<<NPTS/256, 256, 0, stream>>>(pos, rot, ws);
    gsr_qmain  <<<MBLOCKS, 64, 0, stream>>>(scl, opa, ws);
    gsr_qfb    <<<FBLOCKS, 256, 0, stream>>>(opa, ws, (float*)d_out);
}